// Round 7
// baseline (62.730 us; speedup 1.0000x reference)
//
#include <hip/hip_runtime.h>
#include <hip/hip_bf16.h>

#define N_ROWS 8192
#define DIM 128
#define MARGIN_F 0.3f

typedef __attribute__((ext_vector_type(8))) short short8;
typedef __attribute__((ext_vector_type(4))) float f32x4;
typedef __attribute__((ext_vector_type(4))) int int4v;

// ---------------- Kernel A: fp32 -> bf16 (fragment-major), norms, init ----
// Fragment-major layout: 16B unit u = c16*256 + kk*64 + l4*16 + l15 holds
// bf16 elems [kk*32 + l4*8 .. +8) of row (c16*16 + l15). An MFMA A/B-fragment
// load for 16-row panel c16 is xf[c16*256 + kk*64 + lane]: 64 lanes contiguous.
__global__ __launch_bounds__(256) void prep_kernel(
    const float* __restrict__ x, const int* __restrict__ tgt,
    unsigned short* __restrict__ xbB, float2* __restrict__ meta,
    int* __restrict__ apb, int* __restrict__ anb) {
  const int w = threadIdx.x >> 6, l = threadIdx.x & 63;
  const int row = blockIdx.x * 4 + w;
  float2 v = reinterpret_cast<const float2*>(x + (size_t)row * DIM)[l];
  __hip_bfloat16 b0 = __float2bfloat16(v.x);
  __hip_bfloat16 b1 = __float2bfloat16(v.y);
  ushort2 st;
  st.x = *reinterpret_cast<unsigned short*>(&b0);
  st.y = *reinterpret_cast<unsigned short*>(&b1);
  // lane l holds elems 2l,2l+1 = chunk (kk=l>>4, l4=(l>>2)&3), byte (l&3)*4
  const int c16 = row >> 4, l15r = row & 15;
  const int unit = c16 * 256 + (l >> 4) * 64 + ((l >> 2) & 3) * 16 + l15r;
  reinterpret_cast<ushort2*>(xbB)[unit * 4 + (l & 3)] = st;

  float s = v.x * v.x + v.y * v.y;
  #pragma unroll
  for (int off = 32; off >= 1; off >>= 1) s += __shfl_xor(s, off);
  if (l == 0) {
    float2 m;
    m.x = s;
    m.y = __int_as_float(tgt[row]);   // raw bit carry; only ever bit-compared
    meta[row] = m;
    apb[row] = 0x00000000;            // 0.0f (max identity; diagonal is positive)
    anb[row] = 0x7f800000;            // +inf (min identity)
  }
}

// ---------------- Kernel B: symmetric-half Gram + two-sided mining --------
// Upper-triangle 128x128 tiles only: 2080 blocks (vs 4096 full). Each block:
// 4 waves, wave = 32 rows x 128 cols (2 col-subtiles of 64). Row-side mining
// as before; col-side mining (u = sq_r - 2S per column, reduced across the 4
// l4-lanes, atomics) covers the mirrored half. Diagonal blocks skip col-side
// (idempotent duplicate). NO LDS, NO barriers; kk ping-pong B prefetch.
__global__ __launch_bounds__(256, 3) void gram_mine_kernel(
    const unsigned short* __restrict__ xbB, const float2* __restrict__ meta,
    int* __restrict__ apb, int* __restrict__ anb) {
  const int t = threadIdx.x;
  const int w = t >> 6, l = t & 63;
  const int l15 = l & 15, l4 = l >> 4;

  // triangular tile decode (block-uniform): id -> (bi, bj), bi <= bj
  const int NT = 64;
  const int id = blockIdx.x;
  int bi = (int)((2.0f * NT + 1.0f -
                  sqrtf((2.0f * NT + 1.0f) * (2.0f * NT + 1.0f) - 8.0f * (float)id)) * 0.5f);
  while ((bi + 1) * NT - ((bi + 1) * bi) / 2 <= id) ++bi;
  while (bi * NT - (bi * (bi - 1)) / 2 > id) --bi;
  const int bj = bi + (id - (bi * NT - (bi * (bi - 1)) / 2));
  const bool offd = (bi != bj);

  const int rb = bi * 128 + w * 32;        // wave's row base
  const int cbase = bj * 128;              // block's col base (128 cols)

  const short8* xf = reinterpret_cast<const short8*>(xbB);  // 16B units

  // A fragments: panels (rb>>4), (rb>>4)+1 (rows rb..rb+31)
  short8 a0[4], a1[4];
  #pragma unroll
  for (int kk = 0; kk < 4; ++kk) {
    a0[kk] = xf[(rb >> 4) * 256 + kk * 64 + l];
    a1[kk] = xf[((rb >> 4) + 1) * 256 + kk * 64 + l];
  }

  // per-lane row norms + classes (C/D layout rows: rb + rf*16 + l4*4 + rg)
  float sq_r[8]; int t_r[8];
  #pragma unroll
  for (int rf = 0; rf < 2; ++rf)
    #pragma unroll
    for (int rg = 0; rg < 4; ++rg) {
      float2 m = meta[rb + rf * 16 + l4 * 4 + rg];
      sq_r[rf * 4 + rg] = m.x;
      t_r[rf * 4 + rg] = __float_as_int(m.y);
    }

  // row-side mining state on v = sqc - 2*s (row term +sq_r deferred)
  float ap2[8], an2[8];
  #pragma unroll
  for (int i = 0; i < 8; ++i) { ap2[i] = -__builtin_inff(); an2[i] = __builtin_inff(); }

  // B ping-pong buffer over kk; prologue: subtile 0, kk 0
  short8 bb[2][4];
  float2 mc[4];
  const int cb0 = cbase >> 4;
  #pragma unroll
  for (int cf = 0; cf < 4; ++cf) {
    bb[0][cf] = xf[(cb0 + cf) * 256 + l];
    mc[cf] = meta[cbase + cf * 16 + l15];
  }

  #pragma unroll
  for (int st = 0; st < 2; ++st) {
    const int cb16 = (cbase >> 4) + st * 4;
    const int ns = (st < 1) ? 1 : 1;             // next subtile (dead reload at st=1)
    const int nb16 = (cbase >> 4) + ns * 4;

    f32x4 acc[2][4];
    #pragma unroll
    for (int rf = 0; rf < 2; ++rf)
      #pragma unroll
      for (int cf = 0; cf < 4; ++cf) acc[rf][cf] = (f32x4){0.f, 0.f, 0.f, 0.f};

    float2 mn[4];
    #pragma unroll
    for (int kk = 0; kk < 4; ++kk) {
      // prefetch into the other parity: kk+1 of this subtile, or kk=0 of next
      if (kk < 3) {
        #pragma unroll
        for (int cf = 0; cf < 4; ++cf)
          bb[(kk + 1) & 1][cf] = xf[(cb16 + cf) * 256 + (kk + 1) * 64 + l];
      } else {
        #pragma unroll
        for (int cf = 0; cf < 4; ++cf)
          bb[0][cf] = xf[(nb16 + cf) * 256 + l];
        #pragma unroll
        for (int cf = 0; cf < 4; ++cf)
          mn[cf] = meta[cbase + ns * 64 + cf * 16 + l15];
      }
      #pragma unroll
      for (int cf = 0; cf < 4; ++cf) {
        acc[0][cf] = __builtin_amdgcn_mfma_f32_16x16x32_bf16(
            a0[kk], bb[kk & 1][cf], acc[0][cf], 0, 0, 0);
        acc[1][cf] = __builtin_amdgcn_mfma_f32_16x16x32_bf16(
            a1[kk], bb[kk & 1][cf], acc[1][cf], 0, 0, 0);
      }
    }

    // two-sided mining epilogue (runs under next subtile's in-flight loads)
    #pragma unroll
    for (int cf = 0; cf < 4; ++cf) {
      const float sqc = mc[cf].x;
      const int tc = __float_as_int(mc[cf].y);
      float apc = -__builtin_inff(), anc = __builtin_inff();
      #pragma unroll
      for (int rf = 0; rf < 2; ++rf)
        #pragma unroll
        for (int rg = 0; rg < 4; ++rg) {
          int idx = rf * 4 + rg;
          float s2 = acc[rf][cf][rg];
          float v = fmaf(-2.f, s2, sqc);        // row-side tracked value
          float u = fmaf(-2.f, s2, sq_r[idx]);  // col-side tracked value
          bool pos = (t_r[idx] == tc);
          ap2[idx] = pos ? fmaxf(ap2[idx], v) : ap2[idx];
          an2[idx] = pos ? an2[idx] : fminf(an2[idx], v);
          apc = pos ? fmaxf(apc, u) : apc;
          anc = pos ? anc : fminf(anc, u);
        }
      if (offd) {
        // reduce across the 4 l4-lanes holding the same column (l15 fixed)
        apc = fmaxf(apc, __shfl_xor(apc, 16));
        apc = fmaxf(apc, __shfl_xor(apc, 32));
        anc = fminf(anc, __shfl_xor(anc, 16));
        anc = fminf(anc, __shfl_xor(anc, 32));
        if (l4 == 0) {
          int colg = cbase + st * 64 + cf * 16 + l15;
          float a2 = fmaxf(apc + sqc, 1e-12f);
          float n2 = fmaxf(anc + sqc, 1e-12f);
          atomicMax(apb + colg, __float_as_int(a2));
          atomicMin(anb + colg, __float_as_int(n2));
        }
      }
    }
    #pragma unroll
    for (int cf = 0; cf < 4; ++cf) mc[cf] = mn[cf];
  }

  // row-side: reduce across the 16 lanes (same rows, different cols)
  #pragma unroll
  for (int i = 0; i < 8; ++i) {
    #pragma unroll
    for (int off = 1; off < 16; off <<= 1) {
      ap2[i] = fmaxf(ap2[i], __shfl_xor(ap2[i], off));
      an2[i] = fminf(an2[i], __shfl_xor(an2[i], off));
    }
  }
  if (l15 == 0) {
    #pragma unroll
    for (int rf = 0; rf < 2; ++rf)
      #pragma unroll
      for (int rg = 0; rg < 4; ++rg) {
        int row = rb + rf * 16 + l4 * 4 + rg;
        float sqr = meta[row].x;
        // d^2 = v + sq_r; clamp >=1e-12 commutes with max/min; non-negative
        // floats are int-monotone -> int atomics give exact fp max/min.
        float a2 = fmaxf(ap2[rf * 4 + rg] + sqr, 1e-12f);
        float n2 = fmaxf(an2[rf * 4 + rg] + sqr, 1e-12f);
        atomicMax(apb + row, __float_as_int(a2));
        atomicMin(anb + row, __float_as_int(n2));
      }
  }
}

// ---------------- Kernel C: loss = mean(relu(sqrt(ap2)-sqrt(an2)+margin)) --
__global__ __launch_bounds__(1024) void loss_kernel(
    const int4v* __restrict__ apb, const int4v* __restrict__ anb,
    float* __restrict__ out) {
  __shared__ float red[16];
  float s = 0.f;
  for (int i = threadIdx.x; i < N_ROWS / 4; i += 1024) {
    int4v a4 = apb[i], n4 = anb[i];
    #pragma unroll
    for (int j = 0; j < 4; ++j) {
      float ap = sqrtf(__int_as_float(a4[j]));
      float an = sqrtf(__int_as_float(n4[j]));   // +inf sentinel -> relu(-inf)=0
      float li = ap - an + MARGIN_F;
      s += li > 0.f ? li : 0.f;
    }
  }
  #pragma unroll
  for (int off = 32; off >= 1; off >>= 1) s += __shfl_xor(s, off);
  const int w = threadIdx.x >> 6, l = threadIdx.x & 63;
  if (l == 0) red[w] = s;
  __syncthreads();
  if (threadIdx.x < 16) {
    float v = red[threadIdx.x];
    #pragma unroll
    for (int off = 8; off >= 1; off >>= 1) v += __shfl_xor(v, off);
    if (threadIdx.x == 0) out[0] = v / (float)N_ROWS;
  }
}

extern "C" void kernel_launch(void* const* d_in, const int* in_sizes, int n_in,
                              void* d_out, int out_size, void* d_ws, size_t ws_size,
                              hipStream_t stream) {
  const float* x = (const float*)d_in[0];
  const int* tgt = (const int*)d_in[1];
  float* out = (float*)d_out;

  char* ws = (char*)d_ws;
  unsigned short* xbB = (unsigned short*)ws;                // 2 MB fragment-major bf16
  float2* meta = (float2*)(ws + 2097152);                   // 64 KB (sq, tgt)
  int* apb = (int*)(ws + 2097152 + 65536);                  // 32 KB ap^2 bits
  int* anb = (int*)(ws + 2097152 + 65536 + 32768);          // 32 KB an^2 bits

  prep_kernel<<<2048, 256, 0, stream>>>(x, tgt, xbB, meta, apb, anb);
  gram_mine_kernel<<<2080, 256, 0, stream>>>(xbB, meta, apb, anb);
  loss_kernel<<<1, 1024, 0, stream>>>((const int4v*)apb, (const int4v*)anb, out);
}

// Round 8
// 44.276 us; speedup vs baseline: 1.4168x; 1.4168x over previous
//
#include <hip/hip_runtime.h>
#include <hip/hip_bf16.h>

#define N_ROWS 8192
#define DIM 128
#define MARGIN_F 0.3f

typedef __attribute__((ext_vector_type(8))) short short8;
typedef __attribute__((ext_vector_type(4))) float f32x4;
typedef __attribute__((ext_vector_type(4))) int int4v;

// ---------------- Kernel A: fp32 -> bf16 (fragment-major), norms, init ----
// Fragment-major layout: 16B unit u = c16*256 + kk*64 + l4*16 + l15 holds
// bf16 elems [kk*32 + l4*8 .. +8) of row (c16*16 + l15). An MFMA A/B-fragment
// load for 16-row panel c16 is xf[c16*256 + kk*64 + lane]: 64 lanes contiguous.
// xbA holds -2*x (exact bf16 power-of-2 scale) so the Gram MFMA emits
// sqc - 2*s directly when the accumulator is seeded with sqc.
__global__ __launch_bounds__(256) void prep_kernel(
    const float* __restrict__ x, const int* __restrict__ tgt,
    unsigned short* __restrict__ xbA, unsigned short* __restrict__ xbB,
    float2* __restrict__ meta, int* __restrict__ apb, int* __restrict__ anb) {
  const int w = threadIdx.x >> 6, l = threadIdx.x & 63;
  const int row = blockIdx.x * 4 + w;
  float2 v = reinterpret_cast<const float2*>(x + (size_t)row * DIM)[l];
  __hip_bfloat16 b0 = __float2bfloat16(v.x);
  __hip_bfloat16 b1 = __float2bfloat16(v.y);
  __hip_bfloat16 a0 = __float2bfloat16(-2.f * v.x);
  __hip_bfloat16 a1 = __float2bfloat16(-2.f * v.y);
  ushort2 stB, stA;
  stB.x = *reinterpret_cast<unsigned short*>(&b0);
  stB.y = *reinterpret_cast<unsigned short*>(&b1);
  stA.x = *reinterpret_cast<unsigned short*>(&a0);
  stA.y = *reinterpret_cast<unsigned short*>(&a1);
  // lane l holds elems 2l,2l+1 = chunk (kk=l>>4, l4=(l>>2)&3), byte (l&3)*4
  const int c16 = row >> 4, l15r = row & 15;
  const int unit = c16 * 256 + (l >> 4) * 64 + ((l >> 2) & 3) * 16 + l15r;
  reinterpret_cast<ushort2*>(xbB)[unit * 4 + (l & 3)] = stB;
  reinterpret_cast<ushort2*>(xbA)[unit * 4 + (l & 3)] = stA;

  float s = v.x * v.x + v.y * v.y;
  #pragma unroll
  for (int off = 32; off >= 1; off >>= 1) s += __shfl_xor(s, off);
  if (l == 0) {
    float2 m;
    m.x = s;
    m.y = __int_as_float(tgt[row]);   // raw bit carry; only ever bit-compared
    meta[row] = m;
    apb[row] = 0x00000000;            // 0.0f (max identity; diagonal is positive)
    anb[row] = 0x7f800000;            // +inf (min identity)
  }
}

// ---------------- Kernel B: fused Gram (bf16 MFMA) + batch-hard mining -----
// NO LDS, NO barriers. grid (64,8) x 4 waves = 2048 waves = 2/SIMD, no tail.
// Wave = 32 rows x 32 cols per tile, 32 tiles (1024-col chunk). Three-pipe
// software pipeline inside each wave, 2x-unrolled with named registers:
//   MFMA(tile i) -> prefetch B(tile i+1) -> EPILOGUE(tile i-1) -> meta(i+1)
// B loads fly ~350cy before consumption (covers L2 latency in-wave); the
// VALU epilogue overlaps MFMA execution and load latency.
__global__ __launch_bounds__(256, 2) void gram_mine_kernel(
    const unsigned short* __restrict__ xbA, const unsigned short* __restrict__ xbB,
    const float2* __restrict__ meta, int* __restrict__ apb, int* __restrict__ anb) {
  const int t = threadIdx.x;
  const int w = t >> 6, l = t & 63;
  const int l15 = l & 15, l4 = l >> 4;
  const int rb = blockIdx.x * 128 + w * 32;      // wave's global row base
  const int chunk = blockIdx.y * 1024;           // 1024 cols per chunk (32 tiles)
  const int chunkb = chunk >> 4;

  const short8* xfA = reinterpret_cast<const short8*>(xbA);
  const short8* xfB = reinterpret_cast<const short8*>(xbB);

  // A fragments (-2x): panels (rb>>4), (rb>>4)+1 (rows rb..rb+31)
  short8 a0[4], a1[4];
  #pragma unroll
  for (int kk = 0; kk < 4; ++kk) {
    a0[kk] = xfA[(rb >> 4) * 256 + kk * 64 + l];
    a1[kk] = xfA[((rb >> 4) + 1) * 256 + kk * 64 + l];
  }

  // per-lane row classes (C/D layout rows: rb + rf*16 + l4*4 + rg)
  int t_r[8];
  #pragma unroll
  for (int rf = 0; rf < 2; ++rf)
    #pragma unroll
    for (int rg = 0; rg < 4; ++rg)
      t_r[rf * 4 + rg] = __float_as_int(meta[rb + rf * 16 + l4 * 4 + rg].y);

  // mining state on v = sqc - 2*s (row term +sq_r deferred to the end)
  float ap2[8], an2[8];
  #pragma unroll
  for (int i = 0; i < 8; ++i) { ap2[i] = -__builtin_inff(); an2[i] = __builtin_inff(); }

  short8 bb0[8], bb1[8];        // ping-pong full-tile B (tile i in bb[i&1])
  float2 mc0[2], mc1[2];        // (sqc, class) per cf, same parity
  f32x4 accA[2][2], accB[2][2]; // tile i in acc(i&1)

#define PREF_B(IDX, BB) do {                                                  \
    const int cb16_ = chunkb + (IDX) * 2;                                     \
    _Pragma("unroll")                                                         \
    for (int kk_ = 0; kk_ < 4; ++kk_) {                                       \
      BB[kk_ * 2 + 0] = xfB[(cb16_ + 0) * 256 + kk_ * 64 + l];                \
      BB[kk_ * 2 + 1] = xfB[(cb16_ + 1) * 256 + kk_ * 64 + l];                \
    } } while (0)

#define META_L(IDX, MC) do {                                                  \
    MC[0] = meta[chunk + (IDX) * 32 + l15];                                   \
    MC[1] = meta[chunk + (IDX) * 32 + 16 + l15];  } while (0)

#define MFMA_T(BB, MC, ACC) do {                                              \
    _Pragma("unroll")                                                         \
    for (int cf_ = 0; cf_ < 2; ++cf_) {                                       \
      float s_ = MC[cf_].x;                                                   \
      f32x4 ci_ = {s_, s_, s_, s_};                                           \
      ACC[0][cf_] = ci_; ACC[1][cf_] = ci_;                                   \
    }                                                                         \
    _Pragma("unroll")                                                         \
    for (int kk_ = 0; kk_ < 4; ++kk_) {                                       \
      _Pragma("unroll")                                                       \
      for (int cf_ = 0; cf_ < 2; ++cf_) {                                     \
        ACC[0][cf_] = __builtin_amdgcn_mfma_f32_16x16x32_bf16(                \
            a0[kk_], BB[kk_ * 2 + cf_], ACC[0][cf_], 0, 0, 0);                \
        ACC[1][cf_] = __builtin_amdgcn_mfma_f32_16x16x32_bf16(                \
            a1[kk_], BB[kk_ * 2 + cf_], ACC[1][cf_], 0, 0, 0);                \
      } } } while (0)

#define EPI_T(ACC, MC) do {                                                   \
    _Pragma("unroll")                                                         \
    for (int cf_ = 0; cf_ < 2; ++cf_) {                                       \
      const int tc_ = __float_as_int(MC[cf_].y);                              \
      _Pragma("unroll")                                                       \
      for (int rf_ = 0; rf_ < 2; ++rf_) {                                     \
        _Pragma("unroll")                                                     \
        for (int rg_ = 0; rg_ < 4; ++rg_) {                                   \
          const int ix_ = rf_ * 4 + rg_;                                      \
          float v_ = ACC[rf_][cf_][rg_];                                      \
          bool p_ = (t_r[ix_] == tc_);                                        \
          ap2[ix_] = p_ ? fmaxf(ap2[ix_], v_) : ap2[ix_];                     \
          an2[ix_] = p_ ? an2[ix_] : fminf(an2[ix_], v_);                     \
        } } } } while (0)

  // prologue: tile 0
  PREF_B(0, bb0); META_L(0, mc0);
  MFMA_T(bb0, mc0, accA); PREF_B(1, bb1); META_L(1, mc1);

  #pragma unroll 1
  for (int p = 0; p < 15; ++p) {
    const int o = 2 * p + 1;
    // odd tile o: compute; prefetch o+1; finish tile o-1
    MFMA_T(bb1, mc1, accB); PREF_B(o + 1, bb0); EPI_T(accA, mc0); META_L(o + 1, mc0);
    // even tile o+1: compute; prefetch o+2; finish tile o
    MFMA_T(bb0, mc0, accA); PREF_B(o + 2, bb1); EPI_T(accB, mc1); META_L(o + 2, mc1);
  }
  // tile 31 + drain
  MFMA_T(bb1, mc1, accB); EPI_T(accA, mc0); EPI_T(accB, mc1);

#undef PREF_B
#undef META_L
#undef MFMA_T
#undef EPI_T

  // reduce across the 16 lanes (same l4 group = same rows, different cols)
  #pragma unroll
  for (int i = 0; i < 8; ++i) {
    #pragma unroll
    for (int off = 1; off < 16; off <<= 1) {
      ap2[i] = fmaxf(ap2[i], __shfl_xor(ap2[i], off));
      an2[i] = fminf(an2[i], __shfl_xor(an2[i], off));
    }
  }
  if (l15 == 0) {
    #pragma unroll
    for (int rf = 0; rf < 2; ++rf)
      #pragma unroll
      for (int rg = 0; rg < 4; ++rg) {
        int row = rb + rf * 16 + l4 * 4 + rg;
        float sqr = meta[row].x;
        // d^2 = v + sq_r; clamp >=1e-12 commutes with max/min; non-negative
        // floats are int-monotone -> int atomics give exact fp max/min.
        float a2 = fmaxf(ap2[rf * 4 + rg] + sqr, 1e-12f);
        float n2 = fmaxf(an2[rf * 4 + rg] + sqr, 1e-12f);
        atomicMax(apb + row, __float_as_int(a2));
        atomicMin(anb + row, __float_as_int(n2));
      }
  }
}

// ---------------- Kernel C: loss = mean(relu(sqrt(ap2)-sqrt(an2)+margin)) --
__global__ __launch_bounds__(1024) void loss_kernel(
    const int4v* __restrict__ apb, const int4v* __restrict__ anb,
    float* __restrict__ out) {
  __shared__ float red[16];
  float s = 0.f;
  for (int i = threadIdx.x; i < N_ROWS / 4; i += 1024) {
    int4v a4 = apb[i], n4 = anb[i];
    #pragma unroll
    for (int j = 0; j < 4; ++j) {
      float ap = sqrtf(__int_as_float(a4[j]));
      float an = sqrtf(__int_as_float(n4[j]));   // +inf sentinel -> relu(-inf)=0
      float li = ap - an + MARGIN_F;
      s += li > 0.f ? li : 0.f;
    }
  }
  #pragma unroll
  for (int off = 32; off >= 1; off >>= 1) s += __shfl_xor(s, off);
  const int w = threadIdx.x >> 6, l = threadIdx.x & 63;
  if (l == 0) red[w] = s;
  __syncthreads();
  if (threadIdx.x < 16) {
    float v = red[threadIdx.x];
    #pragma unroll
    for (int off = 8; off >= 1; off >>= 1) v += __shfl_xor(v, off);
    if (threadIdx.x == 0) out[0] = v / (float)N_ROWS;
  }
}

extern "C" void kernel_launch(void* const* d_in, const int* in_sizes, int n_in,
                              void* d_out, int out_size, void* d_ws, size_t ws_size,
                              hipStream_t stream) {
  const float* x = (const float*)d_in[0];
  const int* tgt = (const int*)d_in[1];
  float* out = (float*)d_out;

  char* ws = (char*)d_ws;
  unsigned short* xbA = (unsigned short*)ws;                // 2 MB frag-major -2x
  unsigned short* xbB = (unsigned short*)(ws + 2097152);    // 2 MB frag-major  x
  float2* meta = (float2*)(ws + 4194304);                   // 64 KB (sq, tgt)
  int* apb = (int*)(ws + 4194304 + 65536);                  // 32 KB ap^2 bits
  int* anb = (int*)(ws + 4194304 + 65536 + 32768);          // 32 KB an^2 bits

  prep_kernel<<<2048, 256, 0, stream>>>(x, tgt, xbA, xbB, meta, apb, anb);
  gram_mine_kernel<<<dim3(64, 8), 256, 0, stream>>>(xbA, xbB, meta, apb, anb);
  loss_kernel<<<1, 1024, 0, stream>>>((const int4v*)apb, (const int4v*)anb, out);
}

// Round 9
// 44.205 us; speedup vs baseline: 1.4191x; 1.0016x over previous
//
#include <hip/hip_runtime.h>
#include <hip/hip_bf16.h>

#define N_ROWS 8192
#define DIM 128
#define MARGIN_F 0.3f

typedef __attribute__((ext_vector_type(8))) short short8;
typedef __attribute__((ext_vector_type(4))) float f32x4;
typedef __attribute__((ext_vector_type(4))) int int4v;

typedef const void __attribute__((address_space(1)))* gas1_t;
typedef void __attribute__((address_space(3)))* las3_t;

__device__ __forceinline__ void load_lds16(const void* g, void* l) {
  __builtin_amdgcn_global_load_lds((gas1_t)g, (las3_t)l, 16, 0, 0);
}

// ---------------- Kernel A: fp32 -> bf16 (two layouts), norms, init --------
// xbA: fragment-major (-2x) for direct A-register MFMA loads: 16B unit
//   u = c16*256 + kk*64 + l4*16 + l15 holds elems [kk*32+l4*8..+8) of row
//   (c16*16+l15); a panel load is xfA[c16*256 + kk*64 + lane] (contiguous).
// xbBrow: row-major (x), 256 B per row, source for swizzled global_load_lds.
__global__ __launch_bounds__(256) void prep_kernel(
    const float* __restrict__ x, const int* __restrict__ tgt,
    unsigned short* __restrict__ xbA, unsigned short* __restrict__ xbBrow,
    float2* __restrict__ meta, int* __restrict__ apb, int* __restrict__ anb) {
  const int w = threadIdx.x >> 6, l = threadIdx.x & 63;
  const int row = blockIdx.x * 4 + w;
  float2 v = reinterpret_cast<const float2*>(x + (size_t)row * DIM)[l];
  __hip_bfloat16 b0 = __float2bfloat16(v.x);
  __hip_bfloat16 b1 = __float2bfloat16(v.y);
  __hip_bfloat16 a0 = __float2bfloat16(-2.f * v.x);
  __hip_bfloat16 a1 = __float2bfloat16(-2.f * v.y);
  ushort2 stB, stA;
  stB.x = *reinterpret_cast<unsigned short*>(&b0);
  stB.y = *reinterpret_cast<unsigned short*>(&b1);
  stA.x = *reinterpret_cast<unsigned short*>(&a0);
  stA.y = *reinterpret_cast<unsigned short*>(&a1);
  // row-major B copy
  reinterpret_cast<ushort2*>(xbBrow)[(size_t)row * 64 + l] = stB;
  // fragment-major A copy: lane l holds elems 2l,2l+1
  const int c16 = row >> 4, l15r = row & 15;
  const int unit = c16 * 256 + (l >> 4) * 64 + ((l >> 2) & 3) * 16 + l15r;
  reinterpret_cast<ushort2*>(xbA)[unit * 4 + (l & 3)] = stA;

  float s = v.x * v.x + v.y * v.y;
  #pragma unroll
  for (int off = 32; off >= 1; off >>= 1) s += __shfl_xor(s, off);
  if (l == 0) {
    float2 m;
    m.x = s;
    m.y = __int_as_float(tgt[row]);   // raw bit carry; only ever bit-compared
    meta[row] = m;
    apb[row] = 0x00000000;            // 0.0f (max identity; diagonal is positive)
    anb[row] = 0x7f800000;            // +inf (min identity)
  }
}

// ---------------- Kernel B: LDS-shared Gram (bf16 MFMA) + mining -----------
// grid (32 row-blocks, 16 col-chunks) = 512 blocks = 2/CU; block = 8 waves
// (512 thr) -> 4 waves/SIMD resident. Wave = 32 rows; block covers 256 rows
// x 512 cols in 8 slices of 64 cols. B staged ONCE per block per slice via
// global_load_lds (issued at slice top: T14 issue-early => free vmcnt drain)
// into XOR-swizzled LDS shared by all 8 waves (8x L2-traffic cut). A (-2x)
// pinned in registers; acc seeded with sqc so MFMA emits v = sqc - 2s.
__global__ __launch_bounds__(512, 4) void gram_mine_kernel(
    const unsigned short* __restrict__ xbA, const unsigned short* __restrict__ xbBrow,
    const float2* __restrict__ meta, int* __restrict__ apb, int* __restrict__ anb) {
  __shared__ unsigned short Bs[2][64 * 128];   // 2 x 16 KB, swizzled rows

  const int t = threadIdx.x;
  const int w = t >> 6, l = t & 63;
  const int l15 = l & 15, l4 = l >> 4;
  const int rb = blockIdx.x * 256 + w * 32;    // wave's global row base
  const int chunk = blockIdx.y * 512;          // block's col range (8 slices)

  const short8* xfA = reinterpret_cast<const short8*>(xbA);

  // A fragments (-2x): panels (rb>>4), (rb>>4)+1
  short8 a0[4], a1[4];
  #pragma unroll
  for (int kk = 0; kk < 4; ++kk) {
    a0[kk] = xfA[(rb >> 4) * 256 + kk * 64 + l];
    a1[kk] = xfA[((rb >> 4) + 1) * 256 + kk * 64 + l];
  }

  // per-lane row classes (C/D layout rows: rb + rf*16 + l4*4 + rg)
  int t_r[8];
  #pragma unroll
  for (int rf = 0; rf < 2; ++rf)
    #pragma unroll
    for (int rg = 0; rg < 4; ++rg)
      t_r[rf * 4 + rg] = __float_as_int(meta[rb + rf * 16 + l4 * 4 + rg].y);

  // mining state on v = sqc - 2*s (row term +sq_r deferred to the end)
  float ap2[8], an2[8];
  #pragma unroll
  for (int i = 0; i < 8; ++i) { ap2[i] = -__builtin_inff(); an2[i] = __builtin_inff(); }

  // stage slice s (64 cols x 128 k = 16 KB) into Bs[buf]; pre-swizzled source
  auto stage = [&](int buf, int s) {
    const int colbase = chunk + s * 64;
    #pragma unroll
    for (int r = 0; r < 2; ++r) {
      int c = r * 512 + t;                    // 16B-chunk index 0..1023
      int col_local = c >> 4;
      int off = ((c & 15) * 16) ^ ((col_local & 7) << 4);
      const char* src = reinterpret_cast<const char*>(xbBrow) +
                        (size_t)(colbase + col_local) * 256 + off;
      load_lds16(src, (char*)(&Bs[buf][0]) + c * 16);    // linear LDS dest
    }
  };

  // prologue: stage slice 0, load slice-0 meta
  stage(0, 0);
  float2 mcc[4], mcn[4];
  #pragma unroll
  for (int cf = 0; cf < 4; ++cf) mcc[cf] = meta[chunk + cf * 16 + l15];
  __syncthreads();                            // slice 0 staged

  int buf = 0;
  #pragma unroll 1
  for (int s = 0; s < 8; ++s) {
    // T14: issue next slice's staging + meta NOW; consumed after the barrier
    if (s < 7) stage(buf ^ 1, s + 1);
    const int ms = (s < 7) ? (s + 1) : s;
    #pragma unroll
    for (int cf = 0; cf < 4; ++cf) mcn[cf] = meta[chunk + ms * 64 + cf * 16 + l15];

    // seed accumulators with sqc (MFMA then yields v = sqc - 2*s directly)
    f32x4 acc[2][4];
    #pragma unroll
    for (int cf = 0; cf < 4; ++cf) {
      float s_ = mcc[cf].x;
      f32x4 ci = {s_, s_, s_, s_};
      acc[0][cf] = ci; acc[1][cf] = ci;
    }

    __builtin_amdgcn_s_setprio(1);
    #pragma unroll
    for (int kk = 0; kk < 4; ++kk) {
      short8 b[4];
      #pragma unroll
      for (int cf = 0; cf < 4; ++cf) {
        int col_local = cf * 16 + l15;
        int kb = (kk * 64 + l4 * 16) ^ ((col_local & 7) << 4);
        b[cf] = *reinterpret_cast<const short8*>(
            reinterpret_cast<const char*>(&Bs[buf][0]) + col_local * 256 + kb);
      }
      #pragma unroll
      for (int cf = 0; cf < 4; ++cf) {
        acc[0][cf] = __builtin_amdgcn_mfma_f32_16x16x32_bf16(
            a0[kk], b[cf], acc[0][cf], 0, 0, 0);
        acc[1][cf] = __builtin_amdgcn_mfma_f32_16x16x32_bf16(
            a1[kk], b[cf], acc[1][cf], 0, 0, 0);
      }
    }
    __builtin_amdgcn_s_setprio(0);

    // mining epilogue (VALU) — overlaps in-flight staging loads
    #pragma unroll
    for (int cf = 0; cf < 4; ++cf) {
      const int tc = __float_as_int(mcc[cf].y);
      #pragma unroll
      for (int rf = 0; rf < 2; ++rf)
        #pragma unroll
        for (int rg = 0; rg < 4; ++rg) {
          int idx = rf * 4 + rg;
          float v = acc[rf][cf][rg];
          bool pos = (t_r[idx] == tc);
          ap2[idx] = pos ? fmaxf(ap2[idx], v) : ap2[idx];
          an2[idx] = pos ? an2[idx] : fminf(an2[idx], v);
        }
    }

    __syncthreads();     // staged loads long returned (issued ~2500 cyc ago)
    #pragma unroll
    for (int cf = 0; cf < 4; ++cf) mcc[cf] = mcn[cf];
    buf ^= 1;
  }

  // reduce across the 16 lanes (same l4 group = same rows, different cols)
  #pragma unroll
  for (int i = 0; i < 8; ++i) {
    #pragma unroll
    for (int off = 1; off < 16; off <<= 1) {
      ap2[i] = fmaxf(ap2[i], __shfl_xor(ap2[i], off));
      an2[i] = fminf(an2[i], __shfl_xor(an2[i], off));
    }
  }
  if (l15 == 0) {
    #pragma unroll
    for (int rf = 0; rf < 2; ++rf)
      #pragma unroll
      for (int rg = 0; rg < 4; ++rg) {
        int row = rb + rf * 16 + l4 * 4 + rg;
        float sqr = meta[row].x;
        // d^2 = v + sq_r; clamp >=1e-12 commutes with max/min; non-negative
        // floats are int-monotone -> int atomics give exact fp max/min.
        float a2 = fmaxf(ap2[rf * 4 + rg] + sqr, 1e-12f);
        float n2 = fmaxf(an2[rf * 4 + rg] + sqr, 1e-12f);
        atomicMax(apb + row, __float_as_int(a2));
        atomicMin(anb + row, __float_as_int(n2));
      }
  }
}

// ---------------- Kernel C: loss = mean(relu(sqrt(ap2)-sqrt(an2)+margin)) --
__global__ __launch_bounds__(1024) void loss_kernel(
    const int4v* __restrict__ apb, const int4v* __restrict__ anb,
    float* __restrict__ out) {
  __shared__ float red[16];
  float s = 0.f;
  for (int i = threadIdx.x; i < N_ROWS / 4; i += 1024) {
    int4v a4 = apb[i], n4 = anb[i];
    #pragma unroll
    for (int j = 0; j < 4; ++j) {
      float ap = sqrtf(__int_as_float(a4[j]));
      float an = sqrtf(__int_as_float(n4[j]));   // +inf sentinel -> relu(-inf)=0
      float li = ap - an + MARGIN_F;
      s += li > 0.f ? li : 0.f;
    }
  }
  #pragma unroll
  for (int off = 32; off >= 1; off >>= 1) s += __shfl_xor(s, off);
  const int w = threadIdx.x >> 6, l = threadIdx.x & 63;
  if (l == 0) red[w] = s;
  __syncthreads();
  if (threadIdx.x < 16) {
    float v = red[threadIdx.x];
    #pragma unroll
    for (int off = 8; off >= 1; off >>= 1) v += __shfl_xor(v, off);
    if (threadIdx.x == 0) out[0] = v / (float)N_ROWS;
  }
}

extern "C" void kernel_launch(void* const* d_in, const int* in_sizes, int n_in,
                              void* d_out, int out_size, void* d_ws, size_t ws_size,
                              hipStream_t stream) {
  const float* x = (const float*)d_in[0];
  const int* tgt = (const int*)d_in[1];
  float* out = (float*)d_out;

  char* ws = (char*)d_ws;
  unsigned short* xbA = (unsigned short*)ws;                // 2 MB frag-major -2x
  unsigned short* xbBrow = (unsigned short*)(ws + 2097152); // 2 MB row-major x
  float2* meta = (float2*)(ws + 4194304);                   // 64 KB (sq, tgt)
  int* apb = (int*)(ws + 4194304 + 65536);                  // 32 KB ap^2 bits
  int* anb = (int*)(ws + 4194304 + 65536 + 32768);          // 32 KB an^2 bits

  prep_kernel<<<2048, 256, 0, stream>>>(x, tgt, xbA, xbBrow, meta, apb, anb);
  gram_mine_kernel<<<dim3(32, 16), 512, 0, stream>>>(xbA, xbBrow, meta, apb, anb);
  loss_kernel<<<1, 1024, 0, stream>>>((const int4v*)apb, (const int4v*)anb, out);
}